// Round 2
// baseline (209.868 us; speedup 1.0000x reference)
//
#include <hip/hip_runtime.h>
#include <stdint.h>

#define EMBED 1024
#define HEAD  256
#define BATCH 8
#define SEQ   2048
#define NTOK  (BATCH*SEQ)

typedef __attribute__((ext_vector_type(8))) short  s16x8;
typedef __attribute__((ext_vector_type(4))) float  f32x4;
typedef __attribute__((ext_vector_type(4))) unsigned short u16x4;

__device__ __forceinline__ unsigned short f2bf(float f) {
  union { float f; uint32_t u; } v; v.f = f;
  return (unsigned short)((v.u + 0x7FFFu + ((v.u >> 16) & 1u)) >> 16);
}

// ---------------- K0: transpose weights -> Wt bf16 [3][256 h][1024 e] ----------------
__global__ __launch_bounds__(256) void wt_kernel(const float* __restrict__ Wq,
                                                 const float* __restrict__ Wk,
                                                 const float* __restrict__ Wv,
                                                 unsigned short* __restrict__ Wt) {
  int idx = blockIdx.x * 256 + threadIdx.x;   // 0 .. 3*256*1024-1
  int e  = idx & (EMBED - 1);
  int hw = idx >> 10;
  int w  = hw >> 8;
  int h  = hw & 255;
  const float* W = (w == 0) ? Wq : (w == 1) ? Wk : Wv;
  Wt[idx] = f2bf(W[(size_t)e * HEAD + h]);
}

// ---------------- K1: QKV projection GEMM ----------------
#define BM 128
#define BN 256
#define BK 64
#define LDT 72   // padded LDS row length (elems) -> 144B rows, 2-way-free banks

__global__ __launch_bounds__(512) void proj_kernel(const float* __restrict__ x,
    const unsigned short* __restrict__ Wt,
    unsigned short* __restrict__ qo, unsigned short* __restrict__ ko,
    unsigned short* __restrict__ vo) {
  __shared__ unsigned short Al[BM * LDT];
  __shared__ unsigned short Bl[BN * LDT];
  const int tid  = threadIdx.x;
  const int lane = tid & 63;
  const int wid  = tid >> 6;
  const int wm = wid >> 2, wn = wid & 3;   // 2 x 4 waves, each 64x64 out
  const int m0 = blockIdx.x * BM;
  const int w  = blockIdx.y;               // which weight (q/k/v)
  const unsigned short* Wtw = Wt + (size_t)w * 256 * EMBED;

  f32x4 acc[4][4] = {};

  for (int k0 = 0; k0 < EMBED; k0 += BK) {
    __syncthreads();
    // stage A: x fp32 128x64 -> bf16 LDS (2048 float4 units)
    #pragma unroll
    for (int i = 0; i < 4; i++) {
      int u = tid + 512 * i;
      int row = u >> 4, c4 = u & 15;
      f32x4 f = *(const f32x4*)(x + (size_t)(m0 + row) * EMBED + k0 + 4 * c4);
      u16x4 pk;
      pk[0] = f2bf(f[0]); pk[1] = f2bf(f[1]); pk[2] = f2bf(f[2]); pk[3] = f2bf(f[3]);
      *(u16x4*)(&Al[row * LDT + 4 * c4]) = pk;
    }
    // stage B: Wt bf16 256x64 copy (4096 u16x4 units)
    #pragma unroll
    for (int i = 0; i < 8; i++) {
      int u = tid + 512 * i;
      int row = u >> 4, c4 = u & 15;
      *(u16x4*)(&Bl[row * LDT + 4 * c4]) =
          *(const u16x4*)(Wtw + (size_t)row * EMBED + k0 + 4 * c4);
    }
    __syncthreads();
    #pragma unroll
    for (int kk = 0; kk < 2; kk++) {
      s16x8 a[4], b[4];
      #pragma unroll
      for (int mi = 0; mi < 4; mi++) {
        int row = wm * 64 + mi * 16 + (lane & 15);
        a[mi] = *(const s16x8*)(&Al[row * LDT + kk * 32 + 8 * (lane >> 4)]);
      }
      #pragma unroll
      for (int ni = 0; ni < 4; ni++) {
        int row = wn * 64 + ni * 16 + (lane & 15);
        b[ni] = *(const s16x8*)(&Bl[row * LDT + kk * 32 + 8 * (lane >> 4)]);
      }
      #pragma unroll
      for (int mi = 0; mi < 4; mi++)
        #pragma unroll
        for (int ni = 0; ni < 4; ni++)
          acc[mi][ni] = __builtin_amdgcn_mfma_f32_16x16x32_bf16(a[mi], b[ni], acc[mi][ni], 0, 0, 0);
    }
  }

  unsigned short* dst = (w == 0) ? qo : (w == 1) ? ko : vo;
  #pragma unroll
  for (int mi = 0; mi < 4; mi++)
    #pragma unroll
    for (int r = 0; r < 4; r++) {
      int mrow = m0 + wm * 64 + mi * 16 + 4 * (lane >> 4) + r;
      #pragma unroll
      for (int ni = 0; ni < 4; ni++) {
        int col = wn * 64 + ni * 16 + (lane & 15);
        dst[(size_t)mrow * HEAD + col] = f2bf(acc[mi][ni][r]);
      }
    }
}

// ---------------- K2: causal flash attention ----------------
#define QT 32
#define KT 64

__global__ __launch_bounds__(256) void attn_kernel(const unsigned short* __restrict__ qb,
    const unsigned short* __restrict__ kb, const unsigned short* __restrict__ vb,
    float* __restrict__ out) {
  __shared__ unsigned short Kl[KT * 256];   // XOR-swizzled, 32 KB
  __shared__ unsigned short Vt[256 * 72];   // transposed V, padded, 36.9 KB
  __shared__ unsigned short Pl[4][16 * 72]; // per-wave P round-trip
  const int tid  = threadIdx.x;
  const int lane = tid & 63;
  const int wv   = tid >> 6;               // 0..3
  const int b = blockIdx.y;
  const int p = blockIdx.x;                // 0..31 pair index
  const int t1 = p, t2 = 63 - p;           // paired q-tiles: work ~ constant
  const int tw = (wv < 2) ? t1 : t2;       // waves 0,1 -> t1 ; waves 2,3 -> t2
  const unsigned short* qB = qb + (size_t)b * SEQ * HEAD;
  const unsigned short* kB = kb + (size_t)b * SEQ * HEAD;
  const unsigned short* vB = vb + (size_t)b * SEQ * HEAD;
  float* outB = out + (size_t)b * SEQ * HEAD;

  const int rowA = tw * QT + (wv & 1) * 16 + (lane & 15);    // A-layout q row
  const int rowD = tw * QT + (wv & 1) * 16 + 4 * (lane >> 4);// D-layout q row base (+r)

  // hoist Q fragments into registers (16 rows x 256)
  s16x8 qf[8];
  #pragma unroll
  for (int kf = 0; kf < 8; kf++)
    qf[kf] = *(const s16x8*)(qB + (size_t)rowA * HEAD + kf * 32 + 8 * (lane >> 4));

  f32x4 o[16] = {};
  float m[4], lsum[4];
  #pragma unroll
  for (int r = 0; r < 4; r++) { m[r] = -1e30f; lsum[r] = 0.f; }

  const int ntw   = (QT * tw + QT + KT - 1) / KT;
  const int ntmax = (QT * t2 + QT + KT - 1) / KT;  // t2 >= t1 always

  for (int j = 0; j < ntmax; j++) {
    __syncthreads();
    // stage K tile 64x256 bf16 (32 KB), XOR-swizzled rows
    #pragma unroll
    for (int i = 0; i < 8; i++) {
      int u = tid + 256 * i;
      int key = u >> 5, c16 = u & 31;
      s16x8 d = *(const s16x8*)(kB + (size_t)(j * KT + key) * HEAD + c16 * 8);
      int off = (key * 512 + c16 * 16) ^ ((key & 7) << 4);
      *(s16x8*)((char*)Kl + off) = d;
    }
    // stage V tile 64x256 transposed -> Vt[h][key], rows padded to 72 elems
    #pragma unroll
    for (int i = 0; i < 4; i++) {
      int u = tid + 256 * i;
      int key2 = u & 31, hblk = u >> 5;
      const unsigned short* s0 = vB + (size_t)(j * KT + 2 * key2) * HEAD + hblk * 8;
      s16x8 r0 = *(const s16x8*)s0;
      s16x8 r1 = *(const s16x8*)(s0 + HEAD);
      #pragma unroll
      for (int jj = 0; jj < 8; jj++) {
        uint32_t pk = (uint32_t)(unsigned short)r0[jj] | ((uint32_t)(unsigned short)r1[jj] << 16);
        *(uint32_t*)((char*)Vt + (size_t)(hblk * 8 + jj) * 144 + key2 * 4) = pk;
      }
    }
    __syncthreads();
    if (j < ntw) {
      // S = Q K^T  (A=Q regs, B=K from swizzled LDS)
      f32x4 s[4] = {};
      #pragma unroll
      for (int n = 0; n < 4; n++) {
        int key = n * 16 + (lane & 15);
        int swz = (key & 7) << 4;
        #pragma unroll
        for (int kf = 0; kf < 8; kf++) {
          s16x8 kfr = *(const s16x8*)((char*)Kl + ((key * 512 + (lane >> 4) * 16 + kf * 64) ^ swz));
          s[n] = __builtin_amdgcn_mfma_f32_16x16x32_bf16(qf[kf], kfr, s[n], 0, 0, 0);
        }
      }
      const float scale = 0.0625f;  // 1/sqrt(256)
      float mt[4];
      #pragma unroll
      for (int r = 0; r < 4; r++) mt[r] = -1e30f;
      #pragma unroll
      for (int n = 0; n < 4; n++) {
        int key = j * KT + n * 16 + (lane & 15);
        #pragma unroll
        for (int r = 0; r < 4; r++) {
          float sv = s[n][r] * scale;
          sv = (key > rowD + r) ? -1e30f : sv;   // causal mask
          s[n][r] = sv;
          mt[r] = fmaxf(mt[r], sv);
        }
      }
      #pragma unroll
      for (int r = 0; r < 4; r++) {
        #pragma unroll
        for (int xm = 1; xm < 16; xm <<= 1)
          mt[r] = fmaxf(mt[r], __shfl_xor(mt[r], xm));
        float mn = fmaxf(m[r], mt[r]);
        float al = __expf(m[r] - mn);
        m[r] = mn;
        lsum[r] *= al;
        #pragma unroll
        for (int ht = 0; ht < 16; ht++) o[ht][r] *= al;
      }
      float rs[4] = {0.f, 0.f, 0.f, 0.f};
      #pragma unroll
      for (int n = 0; n < 4; n++)
        #pragma unroll
        for (int r = 0; r < 4; r++) {
          float pv = __expf(s[n][r] - m[r]);
          rs[r] += pv;
          Pl[wv][(4 * (lane >> 4) + r) * 72 + n * 16 + (lane & 15)] = f2bf(pv);
        }
      #pragma unroll
      for (int r = 0; r < 4; r++) {
        #pragma unroll
        for (int xm = 1; xm < 16; xm <<= 1)
          rs[r] += __shfl_xor(rs[r], xm);
        lsum[r] += rs[r];
      }
      // P back in A-layout
      s16x8 pa[2];
      #pragma unroll
      for (int kf2 = 0; kf2 < 2; kf2++)
        pa[kf2] = *(const s16x8*)(&Pl[wv][(lane & 15) * 72 + kf2 * 32 + 8 * (lane >> 4)]);
      // O += P V
      #pragma unroll
      for (int ht = 0; ht < 16; ht++) {
        int h = ht * 16 + (lane & 15);
        #pragma unroll
        for (int kf2 = 0; kf2 < 2; kf2++) {
          s16x8 vf = *(const s16x8*)(&Vt[h * 72 + kf2 * 32 + 8 * (lane >> 4)]);
          o[ht] = __builtin_amdgcn_mfma_f32_16x16x32_bf16(pa[kf2], vf, o[ht], 0, 0, 0);
        }
      }
    }
  }
  #pragma unroll
  for (int ht = 0; ht < 16; ht++) {
    int h = ht * 16 + (lane & 15);
    #pragma unroll
    for (int r = 0; r < 4; r++)
      outB[(size_t)(rowD + r) * HEAD + h] = o[ht][r] / lsum[r];
  }
}

extern "C" void kernel_launch(void* const* d_in, const int* in_sizes, int n_in,
                              void* d_out, int out_size, void* d_ws, size_t ws_size,
                              hipStream_t stream) {
  const float* x  = (const float*)d_in[0];
  const float* Wq = (const float*)d_in[1];
  const float* Wk = (const float*)d_in[2];
  const float* Wv = (const float*)d_in[3];
  float* out = (float*)d_out;

  unsigned short* ws = (unsigned short*)d_ws;
  unsigned short* qb = ws;                          // [16384][256] bf16
  unsigned short* kb = qb + (size_t)NTOK * HEAD;
  unsigned short* vb = kb + (size_t)NTOK * HEAD;
  unsigned short* Wt = vb + (size_t)NTOK * HEAD;    // [3][256][1024] bf16
  // total ws use: (3*16384*256 + 3*256*1024) * 2 = ~26.7 MB

  hipLaunchKernelGGL(wt_kernel, dim3(3 * 256 * EMBED / 256), dim3(256), 0, stream,
                     Wq, Wk, Wv, Wt);
  hipLaunchKernelGGL(proj_kernel, dim3(NTOK / BM, 3), dim3(512), 0, stream,
                     x, Wt, qb, kb, vb);
  hipLaunchKernelGGL(attn_kernel, dim3(32, BATCH), dim3(256), 0, stream,
                     qb, kb, vb, out);
}

// Round 3
// 204.802 us; speedup vs baseline: 1.0247x; 1.0247x over previous
//
#include <hip/hip_runtime.h>
#include <stdint.h>

#define EMBED 1024
#define HEAD  256
#define BATCH 8
#define SEQ   2048
#define NTOK  (BATCH*SEQ)

typedef __attribute__((ext_vector_type(8))) short  s16x8;
typedef __attribute__((ext_vector_type(4))) float  f32x4;
typedef __attribute__((ext_vector_type(4))) unsigned short u16x4;

__device__ __forceinline__ unsigned short f2bf(float f) {
  union { float f; uint32_t u; } v; v.f = f;
  return (unsigned short)((v.u + 0x7FFFu + ((v.u >> 16) & 1u)) >> 16);
}

// ---------------- K0: transpose weights -> Wt bf16 [3][256 h][1024 e] ----------------
__global__ __launch_bounds__(256) void wt_kernel(const float* __restrict__ Wq,
                                                 const float* __restrict__ Wk,
                                                 const float* __restrict__ Wv,
                                                 unsigned short* __restrict__ Wt) {
  int idx = blockIdx.x * 256 + threadIdx.x;   // 0 .. 3*256*1024-1
  int e  = idx & (EMBED - 1);
  int hw = idx >> 10;
  int w  = hw >> 8;
  int h  = hw & 255;
  const float* W = (w == 0) ? Wq : (w == 1) ? Wk : Wv;
  Wt[idx] = f2bf(W[(size_t)e * HEAD + h]);
}

// ---------------- K1: QKV projection GEMM ----------------
#define BM 128
#define BN 256
#define BK 64
#define LDT 72   // padded LDS row length (elems)

__global__ __launch_bounds__(512) void proj_kernel(const float* __restrict__ x,
    const unsigned short* __restrict__ Wt,
    unsigned short* __restrict__ qo, unsigned short* __restrict__ ko,
    unsigned short* __restrict__ vt) {
  __shared__ unsigned short Al[BM * LDT];
  __shared__ unsigned short Bl[BN * LDT];
  const int tid  = threadIdx.x;
  const int lane = tid & 63;
  const int wid  = tid >> 6;
  const int wm = wid >> 2, wn = wid & 3;   // 2 x 4 waves, each 64x64 out
  const int m0 = blockIdx.x * BM;
  const int w  = blockIdx.y;               // which weight (q/k/v)
  const unsigned short* Wtw = Wt + (size_t)w * 256 * EMBED;

  f32x4 acc[4][4] = {};

  for (int k0 = 0; k0 < EMBED; k0 += BK) {
    __syncthreads();
    // stage A: x fp32 128x64 -> bf16 LDS (2048 float4 units)
    #pragma unroll
    for (int i = 0; i < 4; i++) {
      int u = tid + 512 * i;
      int row = u >> 4, c4 = u & 15;
      f32x4 f = *(const f32x4*)(x + (size_t)(m0 + row) * EMBED + k0 + 4 * c4);
      u16x4 pk;
      pk[0] = f2bf(f[0]); pk[1] = f2bf(f[1]); pk[2] = f2bf(f[2]); pk[3] = f2bf(f[3]);
      *(u16x4*)(&Al[row * LDT + 4 * c4]) = pk;
    }
    // stage B: Wt bf16 256x64 copy, 16B units (2048 s16x8 units)
    #pragma unroll
    for (int i = 0; i < 4; i++) {
      int u = tid + 512 * i;
      int row = u >> 3, c8 = u & 7;
      *(s16x8*)(&Bl[row * LDT + 8 * c8]) =
          *(const s16x8*)(Wtw + (size_t)row * EMBED + k0 + 8 * c8);
    }
    __syncthreads();
    #pragma unroll
    for (int kk = 0; kk < 2; kk++) {
      s16x8 a[4], b[4];
      #pragma unroll
      for (int mi = 0; mi < 4; mi++) {
        int row = wm * 64 + mi * 16 + (lane & 15);
        a[mi] = *(const s16x8*)(&Al[row * LDT + kk * 32 + 8 * (lane >> 4)]);
      }
      #pragma unroll
      for (int ni = 0; ni < 4; ni++) {
        int row = wn * 64 + ni * 16 + (lane & 15);
        b[ni] = *(const s16x8*)(&Bl[row * LDT + kk * 32 + 8 * (lane >> 4)]);
      }
      #pragma unroll
      for (int mi = 0; mi < 4; mi++)
        #pragma unroll
        for (int ni = 0; ni < 4; ni++)
          acc[mi][ni] = __builtin_amdgcn_mfma_f32_16x16x32_bf16(a[mi], b[ni], acc[mi][ni], 0, 0, 0);
    }
  }

  if (w < 2) {
    unsigned short* dst = (w == 0) ? qo : ko;
    #pragma unroll
    for (int mi = 0; mi < 4; mi++)
      #pragma unroll
      for (int r = 0; r < 4; r++) {
        int mrow = m0 + wm * 64 + mi * 16 + 4 * (lane >> 4) + r;
        #pragma unroll
        for (int ni = 0; ni < 4; ni++) {
          int col = wn * 64 + ni * 16 + (lane & 15);
          dst[(size_t)mrow * HEAD + col] = f2bf(acc[mi][ni][r]);
        }
      }
  } else {
    // V: write TRANSPOSED -> vt[h][token], 8B packed along 4 contiguous rows
    #pragma unroll
    for (int mi = 0; mi < 4; mi++) {
      int base = m0 + wm * 64 + mi * 16 + 4 * (lane >> 4);
      #pragma unroll
      for (int ni = 0; ni < 4; ni++) {
        int col = wn * 64 + ni * 16 + (lane & 15);
        u16x4 pk;
        #pragma unroll
        for (int r = 0; r < 4; r++) pk[r] = f2bf(acc[mi][ni][r]);
        *(u16x4*)(vt + (size_t)col * NTOK + base) = pk;
      }
    }
  }
}

// ---------------- K2: causal flash attention ----------------
#define KT 64

__global__ __launch_bounds__(128) void attn_kernel(const unsigned short* __restrict__ qb,
    const unsigned short* __restrict__ kb, const unsigned short* __restrict__ vt,
    float* __restrict__ out) {
  __shared__ unsigned short Kl[KT * 256];   // XOR-swizzled, 32 KB
  __shared__ unsigned short Pl[2][16 * 72]; // per-wave P round-trip, 4.6 KB
  const int tid  = threadIdx.x;
  const int lane = tid & 63;
  const int wv   = tid >> 6;               // 0,1
  const int bid = blockIdx.x;
  const int b = bid & 7;                   // batch -> XCD affinity
  const int t = 63 - (bid >> 3);           // LPT: biggest causal tiles launch first
  const unsigned short* qB = qb + (size_t)b * SEQ * HEAD;
  const unsigned short* kB = kb + (size_t)b * SEQ * HEAD;
  const unsigned short* vB = vt + (size_t)b * SEQ;    // + h*NTOK + key
  float* outB = out + (size_t)b * SEQ * HEAD;

  const int rowA = t * 32 + wv * 16 + (lane & 15);     // A-layout q row
  const int rowD = t * 32 + wv * 16 + 4 * (lane >> 4); // D-layout q row base (+r)

  // hoist Q fragments (16 rows x 256)
  s16x8 qf[8];
  #pragma unroll
  for (int kf = 0; kf < 8; kf++)
    qf[kf] = *(const s16x8*)(qB + (size_t)rowA * HEAD + kf * 32 + 8 * (lane >> 4));

  f32x4 o[16] = {};
  float m[4], lsum[4];
  #pragma unroll
  for (int r = 0; r < 4; r++) { m[r] = -1e30f; lsum[r] = 0.f; }

  const int nt = (t + 2) >> 1;   // causal KT=64 tiles for 32-row tile t

  for (int j = 0; j < nt; j++) {
    __syncthreads();
    // stage K tile 64x256 bf16 (32 KB), XOR-swizzled rows; 16 units/thread
    #pragma unroll
    for (int i = 0; i < 16; i++) {
      int u = tid + 128 * i;
      int key = u >> 5, c16 = u & 31;
      s16x8 d = *(const s16x8*)(kB + (size_t)(j * KT + key) * HEAD + c16 * 8);
      int off = (key * 512 + c16 * 16) ^ ((key & 7) << 4);
      *(s16x8*)((char*)Kl + off) = d;
    }
    __syncthreads();

    // S = Q K^T
    f32x4 s[4] = {};
    #pragma unroll
    for (int n = 0; n < 4; n++) {
      int key = n * 16 + (lane & 15);
      int swz = (key & 7) << 4;
      #pragma unroll
      for (int kf = 0; kf < 8; kf++) {
        s16x8 kfr = *(const s16x8*)((char*)Kl + ((key * 512 + (lane >> 4) * 16 + kf * 64) ^ swz));
        s[n] = __builtin_amdgcn_mfma_f32_16x16x32_bf16(qf[kf], kfr, s[n], 0, 0, 0);
      }
    }
    const float scale = 0.0625f;  // 1/sqrt(256)
    float mt[4];
    #pragma unroll
    for (int r = 0; r < 4; r++) mt[r] = -1e30f;
    #pragma unroll
    for (int n = 0; n < 4; n++) {
      int key = j * KT + n * 16 + (lane & 15);
      #pragma unroll
      for (int r = 0; r < 4; r++) {
        float sv = s[n][r] * scale;
        sv = (key > rowD + r) ? -1e30f : sv;   // causal mask
        s[n][r] = sv;
        mt[r] = fmaxf(mt[r], sv);
      }
    }
    #pragma unroll
    for (int r = 0; r < 4; r++) {
      #pragma unroll
      for (int xm = 1; xm < 16; xm <<= 1)
        mt[r] = fmaxf(mt[r], __shfl_xor(mt[r], xm));
      float mn = fmaxf(m[r], mt[r]);
      float al = __expf(m[r] - mn);
      m[r] = mn;
      lsum[r] *= al;
      #pragma unroll
      for (int ht = 0; ht < 16; ht++) o[ht][r] *= al;
    }
    float rs[4] = {0.f, 0.f, 0.f, 0.f};
    #pragma unroll
    for (int n = 0; n < 4; n++)
      #pragma unroll
      for (int r = 0; r < 4; r++) {
        float pv = __expf(s[n][r] - m[r]);
        rs[r] += pv;
        Pl[wv][(4 * (lane >> 4) + r) * 72 + n * 16 + (lane & 15)] = f2bf(pv);
      }
    #pragma unroll
    for (int r = 0; r < 4; r++) {
      #pragma unroll
      for (int xm = 1; xm < 16; xm <<= 1)
        rs[r] += __shfl_xor(rs[r], xm);
      lsum[r] += rs[r];
    }
    // P back in A-layout
    s16x8 pa[2];
    #pragma unroll
    for (int kf2 = 0; kf2 < 2; kf2++)
      pa[kf2] = *(const s16x8*)(&Pl[wv][(lane & 15) * 72 + kf2 * 32 + 8 * (lane >> 4)]);
    // O += P V  (V^T fragments straight from global, L2-hot)
    #pragma unroll
    for (int ht = 0; ht < 16; ht++) {
      int h = ht * 16 + (lane & 15);
      #pragma unroll
      for (int kf2 = 0; kf2 < 2; kf2++) {
        s16x8 vf = *(const s16x8*)(vB + (size_t)h * NTOK + j * KT + kf2 * 32 + 8 * (lane >> 4));
        o[ht] = __builtin_amdgcn_mfma_f32_16x16x32_bf16(pa[kf2], vf, o[ht], 0, 0, 0);
      }
    }
  }
  #pragma unroll
  for (int ht = 0; ht < 16; ht++) {
    int h = ht * 16 + (lane & 15);
    #pragma unroll
    for (int r = 0; r < 4; r++)
      outB[(size_t)(rowD + r) * HEAD + h] = o[ht][r] / lsum[r];
  }
}

extern "C" void kernel_launch(void* const* d_in, const int* in_sizes, int n_in,
                              void* d_out, int out_size, void* d_ws, size_t ws_size,
                              hipStream_t stream) {
  const float* x  = (const float*)d_in[0];
  const float* Wq = (const float*)d_in[1];
  const float* Wk = (const float*)d_in[2];
  const float* Wv = (const float*)d_in[3];
  float* out = (float*)d_out;

  unsigned short* ws = (unsigned short*)d_ws;
  unsigned short* qb = ws;                          // [16384][256] bf16
  unsigned short* kb = qb + (size_t)NTOK * HEAD;    // [16384][256]
  unsigned short* vt = kb + (size_t)NTOK * HEAD;    // TRANSPOSED [256 h][16384 tok]
  unsigned short* Wt = vt + (size_t)NTOK * HEAD;    // [3][256][1024] bf16
  // total ws use: (3*16384*256 + 3*256*1024) * 2 = ~26.7 MB

  hipLaunchKernelGGL(wt_kernel, dim3(3 * 256 * EMBED / 256), dim3(256), 0, stream,
                     Wq, Wk, Wv, Wt);
  hipLaunchKernelGGL(proj_kernel, dim3(NTOK / BM, 3), dim3(512), 0, stream,
                     x, Wt, qb, kb, vt);
  hipLaunchKernelGGL(attn_kernel, dim3(512), dim3(128), 0, stream,
                     qb, kb, vt, out);
}